// Round 2
// baseline (286.696 us; speedup 1.0000x reference)
//
#include <hip/hip_runtime.h>
#include <hip/hip_bf16.h>

// Pipeline (bf16 internal, fp32 in/out):
//   cvt:    x fp32 -> xb bf16 (scratch in d_out, dead before gemm2 writes it)
//   transpose#1: w_qkv -> wqkvT bf16 [3072][1024]
//   gemm1:  qkv = xb @ wqkvT^T  (global_load_lds; Q cols scaled 0.125*log2e)
//   transpose_v: qkv V-cols -> vT bf16 [1024][4096]
//   attn:   flash causal, BARRIER-FREE: K/V/Q loaded direct global->register
//           in MFMA fragment layout (L2-resident; LDS pipe was the old wall:
//           18 ds_read_b128 per 16 MFMAs = 176KiB/block-iter ~ 65% of cycles).
//           Each wave owns 32 q-rows (2 strips) -> one K/V fragment fetch
//           feeds 2x MFMAs. LDS holds only the wave-private P roundtrip
//           (16KiB, XOR-swizzled). Consume-then-reload prefetch of K/V frags.
//           grid (16 heads x 32), balanced pairing qt = y<16 ? 31-y : y-16.
//   transpose#2 + gemm2 -> out fp32
// WS (32MiB): qkv [0,24M); wqkvT [24,30M); vT [24,32M) alias after gemm1;
//   yb strided into qkv's dead V cols; wprojT aliases wqkvT after attn.

typedef unsigned short ushort_t;
typedef __attribute__((ext_vector_type(8))) __bf16 bf16x8;
typedef __attribute__((ext_vector_type(8))) unsigned short ushort8;
typedef __attribute__((ext_vector_type(4))) unsigned short ushort4v;
typedef __attribute__((ext_vector_type(4))) float f32x4;

// Swizzled LDS addressing: row stride 64 elems (128B), XOR row bits into
// element bits 3..5 -> b64/b128 column walks hit distinct banks.
#define SWZ(row, e) (((row) << 6) + ((e) ^ (((row) & 7) << 3)))

__device__ inline unsigned short f2bf(float f) {
  union { float f; unsigned int u; } v;
  v.f = f;
  unsigned int r = v.u + 0x7fffu + ((v.u >> 16) & 1u);
  return (unsigned short)(r >> 16);
}

__device__ __forceinline__ void gl_lds16(const void* g, void* l) {
  __builtin_amdgcn_global_load_lds((const __attribute__((address_space(1))) void*)g,
                                   (__attribute__((address_space(3))) void*)l, 16, 0, 0);
}

// x fp32 -> bf16, 4 elems/thread
__global__ __launch_bounds__(256) void cvt_f32_bf16(const float* __restrict__ in,
                                                    ushort_t* __restrict__ out) {
  const size_t i = ((size_t)blockIdx.x * 256 + threadIdx.x) * 4;
  const float4 v = *(const float4*)(in + i);
  ushort4v o;
  o.x = f2bf(v.x); o.y = f2bf(v.y); o.z = f2bf(v.z); o.w = f2bf(v.w);
  *(ushort4v*)(out + i) = o;
}

// in fp32 [R][C] -> out bf16 [C][R]
__global__ __launch_bounds__(256) void transpose_f32_bf16(const float* __restrict__ in,
                                                          ushort_t* __restrict__ out,
                                                          int R, int C) {
  __shared__ ushort_t tile[32][33];
  const int r0 = blockIdx.y * 32, c0 = blockIdx.x * 32;
  const int tx = threadIdx.x, ty = threadIdx.y;  // block (32,8)
  #pragma unroll
  for (int j = 0; j < 32; j += 8)
    tile[ty + j][tx] = f2bf(in[(size_t)(r0 + ty + j) * C + c0 + tx]);
  __syncthreads();
  #pragma unroll
  for (int j = 0; j < 32; j += 8)
    out[(size_t)(c0 + ty + j) * R + r0 + tx] = tile[tx][ty + j];
}

// bf16 [rows, stride in_ld] -> bf16 [cols, stride out_ld]
__global__ __launch_bounds__(256) void transpose_bf16_ld(const ushort_t* __restrict__ in,
                                                         ushort_t* __restrict__ out,
                                                         int in_ld, int out_ld) {
  __shared__ ushort_t tile[32][33];
  const int r0 = blockIdx.y * 32, c0 = blockIdx.x * 32;
  const int tx = threadIdx.x, ty = threadIdx.y;
  #pragma unroll
  for (int j = 0; j < 32; j += 8)
    tile[ty + j][tx] = in[(size_t)(r0 + ty + j) * in_ld + c0 + tx];
  __syncthreads();
  #pragma unroll
  for (int j = 0; j < 32; j += 8)
    out[(size_t)(c0 + ty + j) * out_ld + r0 + tx] = tile[tx][ty + j];
}

// C bf16 = A(bf16) @ Bt^T, both staged async. Q-scale on blockIdx.x<8 (cols<1024).
__global__ __launch_bounds__(256) void gemm_bt_bf16out(const ushort_t* __restrict__ A,
                                                       const ushort_t* __restrict__ Bt,
                                                       ushort_t* __restrict__ C,
                                                       int M, int N, int K) {
  __shared__ __attribute__((aligned(16))) ushort_t As[128 * 64];
  __shared__ __attribute__((aligned(16))) ushort_t Bs[128 * 64];
  const int tid = threadIdx.x;
  const int lane = tid & 63;
  const int wave = tid >> 6;
  const int wy = wave >> 1, wx = wave & 1;
  const int quad = lane >> 4, l16 = lane & 15;
  const size_t bm = (size_t)blockIdx.y * 128;
  const size_t bn = (size_t)blockIdx.x * 128;

  const f32x4 fzero = {0.f, 0.f, 0.f, 0.f};
  f32x4 acc[4][4];
  #pragma unroll
  for (int i = 0; i < 4; ++i)
    #pragma unroll
    for (int j = 0; j < 4; ++j) acc[i][j] = fzero;

  for (int k0 = 0; k0 < K; k0 += 64) {
    #pragma unroll
    for (int i = 0; i < 4; ++i) {
      int c = (wave * 4 + i) * 64 + lane;
      int row = c >> 3, col = (c & 7) * 8;
      gl_lds16(A + (bm + row) * K + k0 + col, As + c * 8);
      gl_lds16(Bt + (bn + row) * K + k0 + col, Bs + c * 8);
    }
    __syncthreads();
    #pragma unroll
    for (int ks = 0; ks < 2; ++ks) {
      bf16x8 af[4], bb[4];
      #pragma unroll
      for (int mt = 0; mt < 4; ++mt)
        af[mt] = *(const bf16x8*)(As + (wy * 64 + mt * 16 + l16) * 64 + ks * 32 + quad * 8);
      #pragma unroll
      for (int nt = 0; nt < 4; ++nt)
        bb[nt] = *(const bf16x8*)(Bs + (wx * 64 + nt * 16 + l16) * 64 + ks * 32 + quad * 8);
      #pragma unroll
      for (int mt = 0; mt < 4; ++mt)
        #pragma unroll
        for (int nt = 0; nt < 4; ++nt)
          acc[mt][nt] = __builtin_amdgcn_mfma_f32_16x16x32_bf16(af[mt], bb[nt], acc[mt][nt], 0, 0, 0);
    }
    __syncthreads();
  }
  const float sc = (blockIdx.x < 8) ? 0.18033688f : 1.0f;  // 0.125*log2(e) for Q cols
  #pragma unroll
  for (int mt = 0; mt < 4; ++mt)
    #pragma unroll
    for (int nt = 0; nt < 4; ++nt)
      #pragma unroll
      for (int r = 0; r < 4; ++r)
        C[(bm + wy * 64 + mt * 16 + quad * 4 + r) * N + bn + wx * 64 + nt * 16 + l16] =
            f2bf(acc[mt][nt][r] * sc);
}

// A bf16 [M][K] row stride lda, Bt bf16 [N][K], C fp32. Both async.
__global__ __launch_bounds__(256) void gemm_bt_f32out(const ushort_t* __restrict__ A,
                                                      const ushort_t* __restrict__ Bt,
                                                      float* __restrict__ C,
                                                      int M, int N, int K, int lda) {
  __shared__ __attribute__((aligned(16))) ushort_t As[128 * 64];
  __shared__ __attribute__((aligned(16))) ushort_t Bs[128 * 64];
  const int tid = threadIdx.x;
  const int lane = tid & 63;
  const int wave = tid >> 6;
  const int wy = wave >> 1, wx = wave & 1;
  const int quad = lane >> 4, l16 = lane & 15;
  const size_t bm = (size_t)blockIdx.y * 128;
  const size_t bn = (size_t)blockIdx.x * 128;

  const f32x4 fzero = {0.f, 0.f, 0.f, 0.f};
  f32x4 acc[4][4];
  #pragma unroll
  for (int i = 0; i < 4; ++i)
    #pragma unroll
    for (int j = 0; j < 4; ++j) acc[i][j] = fzero;

  for (int k0 = 0; k0 < K; k0 += 64) {
    #pragma unroll
    for (int i = 0; i < 4; ++i) {
      int c = (wave * 4 + i) * 64 + lane;
      int row = c >> 3, col = (c & 7) * 8;
      gl_lds16(A + (bm + row) * lda + k0 + col, As + c * 8);
      gl_lds16(Bt + (bn + row) * K + k0 + col, Bs + c * 8);
    }
    __syncthreads();
    #pragma unroll
    for (int ks = 0; ks < 2; ++ks) {
      bf16x8 af[4], bb[4];
      #pragma unroll
      for (int mt = 0; mt < 4; ++mt)
        af[mt] = *(const bf16x8*)(As + (wy * 64 + mt * 16 + l16) * 64 + ks * 32 + quad * 8);
      #pragma unroll
      for (int nt = 0; nt < 4; ++nt)
        bb[nt] = *(const bf16x8*)(Bs + (wx * 64 + nt * 16 + l16) * 64 + ks * 32 + quad * 8);
      #pragma unroll
      for (int mt = 0; mt < 4; ++mt)
        #pragma unroll
        for (int nt = 0; nt < 4; ++nt)
          acc[mt][nt] = __builtin_amdgcn_mfma_f32_16x16x32_bf16(af[mt], bb[nt], acc[mt][nt], 0, 0, 0);
    }
    __syncthreads();
  }
  #pragma unroll
  for (int mt = 0; mt < 4; ++mt)
    #pragma unroll
    for (int nt = 0; nt < 4; ++nt)
      #pragma unroll
      for (int r = 0; r < 4; ++r)
        C[(bm + wy * 64 + mt * 16 + quad * 4 + r) * N + bn + wx * 64 + nt * 16 + l16] =
            acc[mt][nt][r];
}

// exp2 + causal mask one 16-row strip of S^T; write P to swizzled LDS; return l-partial.
__device__ __forceinline__ float strip_exp_store(ushort_t* Ps, const f32x4* s, int kb,
                                                 int sbase, int srowPs, int quad, int l16) {
  const bool masked = (kb + 63 > sbase);  // wave-uniform per strip
  float la = 0.f, lb = 0.f;               // split accumulators: halve add chain
  #pragma unroll
  for (int nt = 0; nt < 4; ++nt) {
    ushort4v pv;
    #pragma unroll
    for (int r = 0; r < 4; ++r) {
      float xv = s[nt][r];
      if (masked) {
        int kkg = kb + nt * 16 + quad * 4 + r;
        xv = (kkg <= sbase + l16) ? xv : -30000.f;
      }
      union { float f; unsigned int u; } p;
      p.f = exp2f(xv);
      if (r & 1) lb += p.f; else la += p.f;
      pv[r] = (ushort_t)(p.u >> 16);  // truncate (p >= 0)
    }
    *(ushort4v*)(Ps + SWZ(srowPs, nt * 16 + quad * 4)) = pv;
  }
  return la + lb;
}

// Flash causal attention, BARRIER-FREE. 256 threads = 4 waves, each wave owns
// 32 q-rows (2 strips of 16). Block covers 128 q-rows; grid (16 heads, 32);
// balanced pairing qt = y<16 ? 31-y : y-16 (CU pair sums to 66 tile-iters).
// K/V loaded per-wave straight from global into MFMA A-fragment registers
// (consume-then-reload prefetch: kf refilled after QK, vf after PV — latency
// hides under the other phases). LDS = P roundtrip only (wave-private rows,
// XOR-swizzled, no barrier: in-wave ds_write->ds_read ordering via lgkmcnt).
// Per-wave tile count ntw trims the fully-masked last tile for waves 0-1.
__global__ __launch_bounds__(256, 2) void attn_fwd(const ushort_t* __restrict__ qkv,
                                                   const ushort_t* __restrict__ vT,
                                                   ushort_t* __restrict__ y) {
  __shared__ __attribute__((aligned(16))) ushort_t Ps[128 * 64];
  const int head = blockIdx.x;
  const int by = blockIdx.y;
  const int qt = (by < 16) ? (31 - by) : (by - 16);  // balanced CU pairing
  const int qb = qt * 128;
  const int tid = threadIdx.x;
  const int lane = tid & 63, wave = tid >> 6;  // 4 waves
  const int quad = lane >> 4, l16 = lane & 15;
  const int hoff = head * 64;
  const int wrow = wave * 32;                      // wave's q-row base in tile
  const int ntw = 2 * qt + 1 + (wave >> 1);        // waves 0,1 skip dead last tile

  // per-lane invariant offsets (elements)
  const int koff = l16 * 3072 + 1024 + hoff + quad * 8;  // K frag: +(kb+nt*16)*3072 +ks*32
  const int voff = (hoff + l16) * 4096 + quad * 8;       // V frag: +nt*16*4096 +kb +ks*32

  // Q fragments (B-operand), loaded once: bq[strip][ks]
  bf16x8 bq[2][2];
  #pragma unroll
  for (int st = 0; st < 2; ++st)
    #pragma unroll
    for (int ks = 0; ks < 2; ++ks)
      bq[st][ks] = *(const bf16x8*)(qkv + (qb + wrow + st * 16 + l16) * 3072 + hoff +
                                    ks * 32 + quad * 8);

  // K/V fragments for tile 0
  bf16x8 kf[2][4], vf[2][4];
  #pragma unroll
  for (int ks = 0; ks < 2; ++ks)
    #pragma unroll
    for (int nt = 0; nt < 4; ++nt) {
      kf[ks][nt] = *(const bf16x8*)(qkv + (nt * 16) * 3072 + ks * 32 + koff);
      vf[ks][nt] = *(const bf16x8*)(vT + (nt * 16) * 4096 + ks * 32 + voff);
    }

  const f32x4 fzero = {0.f, 0.f, 0.f, 0.f};
  f32x4 o0[4], o1[4];
  #pragma unroll
  for (int nt = 0; nt < 4; ++nt) { o0[nt] = fzero; o1[nt] = fzero; }
  float lp0 = 0.f, lp1 = 0.f;

  for (int t = 0; t < ntw; ++t) {
    const int kb = t * 64;
    // S^T = K Q^T for both strips (K frags shared)
    f32x4 s0[4], s1[4];
    #pragma unroll
    for (int nt = 0; nt < 4; ++nt) { s0[nt] = fzero; s1[nt] = fzero; }
    __builtin_amdgcn_s_setprio(1);
    #pragma unroll
    for (int ks = 0; ks < 2; ++ks)
      #pragma unroll
      for (int nt = 0; nt < 4; ++nt) {
        s0[nt] = __builtin_amdgcn_mfma_f32_16x16x32_bf16(kf[ks][nt], bq[0][ks], s0[nt], 0, 0, 0);
        s1[nt] = __builtin_amdgcn_mfma_f32_16x16x32_bf16(kf[ks][nt], bq[1][ks], s1[nt], 0, 0, 0);
      }
    __builtin_amdgcn_s_setprio(0);

    // prefetch next tile's K frags (hides under exp + PV)
    const int kn = (t + 1 < ntw) ? (t + 1) * 64 : 0;
    #pragma unroll
    for (int ks = 0; ks < 2; ++ks)
      #pragma unroll
      for (int nt = 0; nt < 4; ++nt)
        kf[ks][nt] = *(const bf16x8*)(qkv + (kn + nt * 16) * 3072 + ks * 32 + koff);

    // P = exp2(S^T) with causal mask; write to wave-private swizzled LDS
    lp0 += strip_exp_store(Ps, s0, kb, qb + wrow, wrow + l16, quad, l16);
    lp1 += strip_exp_store(Ps, s1, kb, qb + wrow + 16, wrow + 16 + l16, quad, l16);

    // O^T += V^T P^T
    __builtin_amdgcn_s_setprio(1);
    #pragma unroll
    for (int ks = 0; ks < 2; ++ks) {
      bf16x8 bp0 = *(const bf16x8*)(Ps + SWZ(wrow + l16, ks * 32 + quad * 8));
      bf16x8 bp1 = *(const bf16x8*)(Ps + SWZ(wrow + 16 + l16, ks * 32 + quad * 8));
      #pragma unroll
      for (int nt = 0; nt < 4; ++nt) {
        o0[nt] = __builtin_amdgcn_mfma_f32_16x16x32_bf16(vf[ks][nt], bp0, o0[nt], 0, 0, 0);
        o1[nt] = __builtin_amdgcn_mfma_f32_16x16x32_bf16(vf[ks][nt], bp1, o1[nt], 0, 0, 0);
      }
    }
    __builtin_amdgcn_s_setprio(0);

    // prefetch next tile's V frags (hides under next QK + exp)
    #pragma unroll
    for (int ks = 0; ks < 2; ++ks)
      #pragma unroll
      for (int nt = 0; nt < 4; ++nt)
        vf[ks][nt] = *(const bf16x8*)(vT + (nt * 16) * 4096 + kn + ks * 32 + voff);
  }

  // l: reduce per-lane partials across the 4 quads (same l16), per strip
  lp0 += __shfl_xor(lp0, 16); lp0 += __shfl_xor(lp0, 32);
  lp1 += __shfl_xor(lp1, 16); lp1 += __shfl_xor(lp1, 32);
  const float inv0 = 1.0f / lp0;
  const float inv1 = 1.0f / lp1;
  // o[nt][r] = O[q][d = nt*16+quad*4+r] -> packed stores
  #pragma unroll
  for (int nt = 0; nt < 4; ++nt) {
    ushort4v ov0, ov1;
    #pragma unroll
    for (int r = 0; r < 4; ++r) {
      ov0[r] = f2bf(o0[nt][r] * inv0);
      ov1[r] = f2bf(o1[nt][r] * inv1);
    }
    *(ushort4v*)(y + (size_t)(qb + wrow + l16) * 3072 + hoff + nt * 16 + quad * 4) = ov0;
    *(ushort4v*)(y + (size_t)(qb + wrow + 16 + l16) * 3072 + hoff + nt * 16 + quad * 4) = ov1;
  }
}

extern "C" void kernel_launch(void* const* d_in, const int* in_sizes, int n_in,
                              void* d_out, int out_size, void* d_ws, size_t ws_size,
                              hipStream_t stream) {
  const float* x = (const float*)d_in[0];       // [4096][1024] fp32
  const float* w_qkv = (const float*)d_in[1];   // [1024][3072] fp32
  const float* w_proj = (const float*)d_in[2];  // [1024][1024] fp32
  float* out = (float*)d_out;                   // [4096][1024] fp32

  ushort_t* ws = (ushort_t*)d_ws;
  ushort_t* qkv = ws;                            // [4096][3072]  [0, 24 MiB)
  ushort_t* wqkvT = ws + (size_t)4096 * 3072;    // [3072][1024]  [24, 30 MiB)
  ushort_t* vT = wqkvT;                          // [1024][4096]  [24, 32 MiB) alias after gemm1
  ushort_t* yb = qkv + 2048;                     // strided view into dead V cols (ld 3072)
  ushort_t* wprojT = wqkvT;                      // alias after attn
  ushort_t* xb = (ushort_t*)d_out;               // x bf16 scratch in d_out (dead before gemm2)

  cvt_f32_bf16<<<4096, 256, 0, stream>>>(x, xb);
  transpose_f32_bf16<<<dim3(96, 32), dim3(32, 8), 0, stream>>>(w_qkv, wqkvT, 1024, 3072);
  gemm_bt_bf16out<<<dim3(24, 32), 256, 0, stream>>>(xb, wqkvT, qkv, 4096, 3072, 1024);
  transpose_bf16_ld<<<dim3(32, 128), dim3(32, 8), 0, stream>>>(qkv + 2048, vT, 3072, 4096);
  attn_fwd<<<dim3(16, 32), 256, 0, stream>>>(qkv, vT, yb);
  transpose_f32_bf16<<<dim3(32, 32), dim3(32, 8), 0, stream>>>(w_proj, wprojT, 1024, 1024);
  gemm_bt_f32out<<<dim3(8, 32), 256, 0, stream>>>(yb, wprojT, out, 4096, 1024, 1024, 3072);
}

// Round 4
// 249.916 us; speedup vs baseline: 1.1472x; 1.1472x over previous
//
#include <hip/hip_runtime.h>
#include <hip/hip_bf16.h>

// Pipeline (bf16 internal, fp32 in/out):
//   cvt:    x fp32 -> xb bf16 (scratch in d_out, dead before gemm2 writes it)
//   transpose#1: w_qkv -> wqkvT bf16 [3072][1024]
//   gemm1:  qkv = xb @ wqkvT^T  (global_load_lds; Q cols scaled 0.125*log2e)
//   transpose_v: qkv V-cols -> vT bf16 [1024][4096]
//   attn:   flash causal, LDS-staged double-buffered K/V (R1 structure — the
//           global->reg variant regressed: 16-row scattered VMEM + 4x L2
//           amplification + latency exposure). NEW vs R1:
//           * 4 waves x 32 q-rows (2 strips): K/V frags read once from LDS,
//             reused for both strips -> LDS bytes/MFMA 1.25KB -> 0.7KB.
//           * softmax: raw v_exp_f32 (inline asm) + v_cvt_pk_bf16_f32 packing;
//             l computed via MFMA with all-ones A-frag (kills 32 adds/lane
//             per iter + the final cross-quad shuffle reduce).
//           * 48KiB LDS + launch_bounds(256,3) -> 3 blocks/CU (12 waves).
//           grid (16 heads x 32), balanced pairing qt = y<16 ? 31-y : y-16.
//           Wave-uniform compute guard trims the fully-masked last tile for
//           waves 0-1 (barrier count stays uniform).
//   transpose#2 + gemm2 -> out fp32
// WS (32MiB): qkv [0,24M); wqkvT [24,30M); vT [24,32M) alias after gemm1;
//   yb strided into qkv's dead V cols; wprojT aliases wqkvT after attn.

typedef unsigned short ushort_t;
typedef __attribute__((ext_vector_type(8))) __bf16 bf16x8;
typedef __attribute__((ext_vector_type(8))) unsigned short ushort8;
typedef __attribute__((ext_vector_type(4))) unsigned short ushort4v;
typedef __attribute__((ext_vector_type(4))) float f32x4;

// Swizzled LDS addressing: row stride 64 elems (128B), XOR row bits into
// element bits 3..5 -> b64/b128 column walks hit distinct banks.
#define SWZ(row, e) (((row) << 6) + ((e) ^ (((row) & 7) << 3)))

__device__ inline unsigned short f2bf(float f) {
  union { float f; unsigned int u; } v;
  v.f = f;
  unsigned int r = v.u + 0x7fffu + ((v.u >> 16) & 1u);
  return (unsigned short)(r >> 16);
}

__device__ __forceinline__ float fast_exp2(float x) {
  float r;
  asm("v_exp_f32 %0, %1" : "=v"(r) : "v"(x));  // 2^x, inputs bounded by mask
  return r;
}

__device__ __forceinline__ void gl_lds16(const void* g, void* l) {
  __builtin_amdgcn_global_load_lds((const __attribute__((address_space(1))) void*)g,
                                   (__attribute__((address_space(3))) void*)l, 16, 0, 0);
}

// x fp32 -> bf16, 4 elems/thread
__global__ __launch_bounds__(256) void cvt_f32_bf16(const float* __restrict__ in,
                                                    ushort_t* __restrict__ out) {
  const size_t i = ((size_t)blockIdx.x * 256 + threadIdx.x) * 4;
  const float4 v = *(const float4*)(in + i);
  ushort4v o;
  o.x = f2bf(v.x); o.y = f2bf(v.y); o.z = f2bf(v.z); o.w = f2bf(v.w);
  *(ushort4v*)(out + i) = o;
}

// in fp32 [R][C] -> out bf16 [C][R]
__global__ __launch_bounds__(256) void transpose_f32_bf16(const float* __restrict__ in,
                                                          ushort_t* __restrict__ out,
                                                          int R, int C) {
  __shared__ ushort_t tile[32][33];
  const int r0 = blockIdx.y * 32, c0 = blockIdx.x * 32;
  const int tx = threadIdx.x, ty = threadIdx.y;  // block (32,8)
  #pragma unroll
  for (int j = 0; j < 32; j += 8)
    tile[ty + j][tx] = f2bf(in[(size_t)(r0 + ty + j) * C + c0 + tx]);
  __syncthreads();
  #pragma unroll
  for (int j = 0; j < 32; j += 8)
    out[(size_t)(c0 + ty + j) * R + r0 + tx] = tile[tx][ty + j];
}

// bf16 [rows, stride in_ld] -> bf16 [cols, stride out_ld]
__global__ __launch_bounds__(256) void transpose_bf16_ld(const ushort_t* __restrict__ in,
                                                         ushort_t* __restrict__ out,
                                                         int in_ld, int out_ld) {
  __shared__ ushort_t tile[32][33];
  const int r0 = blockIdx.y * 32, c0 = blockIdx.x * 32;
  const int tx = threadIdx.x, ty = threadIdx.y;
  #pragma unroll
  for (int j = 0; j < 32; j += 8)
    tile[ty + j][tx] = in[(size_t)(r0 + ty + j) * in_ld + c0 + tx];
  __syncthreads();
  #pragma unroll
  for (int j = 0; j < 32; j += 8)
    out[(size_t)(c0 + ty + j) * out_ld + r0 + tx] = tile[tx][ty + j];
}

// C bf16 = A(bf16) @ Bt^T, both staged async. Q-scale on blockIdx.x<8 (cols<1024).
__global__ __launch_bounds__(256) void gemm_bt_bf16out(const ushort_t* __restrict__ A,
                                                       const ushort_t* __restrict__ Bt,
                                                       ushort_t* __restrict__ C,
                                                       int M, int N, int K) {
  __shared__ __attribute__((aligned(16))) ushort_t As[128 * 64];
  __shared__ __attribute__((aligned(16))) ushort_t Bs[128 * 64];
  const int tid = threadIdx.x;
  const int lane = tid & 63;
  const int wave = tid >> 6;
  const int wy = wave >> 1, wx = wave & 1;
  const int quad = lane >> 4, l16 = lane & 15;
  const size_t bm = (size_t)blockIdx.y * 128;
  const size_t bn = (size_t)blockIdx.x * 128;

  const f32x4 fzero = {0.f, 0.f, 0.f, 0.f};
  f32x4 acc[4][4];
  #pragma unroll
  for (int i = 0; i < 4; ++i)
    #pragma unroll
    for (int j = 0; j < 4; ++j) acc[i][j] = fzero;

  for (int k0 = 0; k0 < K; k0 += 64) {
    #pragma unroll
    for (int i = 0; i < 4; ++i) {
      int c = (wave * 4 + i) * 64 + lane;
      int row = c >> 3, col = (c & 7) * 8;
      gl_lds16(A + (bm + row) * K + k0 + col, As + c * 8);
      gl_lds16(Bt + (bn + row) * K + k0 + col, Bs + c * 8);
    }
    __syncthreads();
    #pragma unroll
    for (int ks = 0; ks < 2; ++ks) {
      bf16x8 af[4], bb[4];
      #pragma unroll
      for (int mt = 0; mt < 4; ++mt)
        af[mt] = *(const bf16x8*)(As + (wy * 64 + mt * 16 + l16) * 64 + ks * 32 + quad * 8);
      #pragma unroll
      for (int nt = 0; nt < 4; ++nt)
        bb[nt] = *(const bf16x8*)(Bs + (wx * 64 + nt * 16 + l16) * 64 + ks * 32 + quad * 8);
      #pragma unroll
      for (int mt = 0; mt < 4; ++mt)
        #pragma unroll
        for (int nt = 0; nt < 4; ++nt)
          acc[mt][nt] = __builtin_amdgcn_mfma_f32_16x16x32_bf16(af[mt], bb[nt], acc[mt][nt], 0, 0, 0);
    }
    __syncthreads();
  }
  const float sc = (blockIdx.x < 8) ? 0.18033688f : 1.0f;  // 0.125*log2(e) for Q cols
  #pragma unroll
  for (int mt = 0; mt < 4; ++mt)
    #pragma unroll
    for (int nt = 0; nt < 4; ++nt)
      #pragma unroll
      for (int r = 0; r < 4; ++r)
        C[(bm + wy * 64 + mt * 16 + quad * 4 + r) * N + bn + wx * 64 + nt * 16 + l16] =
            f2bf(acc[mt][nt][r] * sc);
}

// A bf16 [M][K] row stride lda, Bt bf16 [N][K], C fp32. Both async.
__global__ __launch_bounds__(256) void gemm_bt_f32out(const ushort_t* __restrict__ A,
                                                      const ushort_t* __restrict__ Bt,
                                                      float* __restrict__ C,
                                                      int M, int N, int K, int lda) {
  __shared__ __attribute__((aligned(16))) ushort_t As[128 * 64];
  __shared__ __attribute__((aligned(16))) ushort_t Bs[128 * 64];
  const int tid = threadIdx.x;
  const int lane = tid & 63;
  const int wave = tid >> 6;
  const int wy = wave >> 1, wx = wave & 1;
  const int quad = lane >> 4, l16 = lane & 15;
  const size_t bm = (size_t)blockIdx.y * 128;
  const size_t bn = (size_t)blockIdx.x * 128;

  const f32x4 fzero = {0.f, 0.f, 0.f, 0.f};
  f32x4 acc[4][4];
  #pragma unroll
  for (int i = 0; i < 4; ++i)
    #pragma unroll
    for (int j = 0; j < 4; ++j) acc[i][j] = fzero;

  for (int k0 = 0; k0 < K; k0 += 64) {
    #pragma unroll
    for (int i = 0; i < 4; ++i) {
      int c = (wave * 4 + i) * 64 + lane;
      int row = c >> 3, col = (c & 7) * 8;
      gl_lds16(A + (bm + row) * lda + k0 + col, As + c * 8);
      gl_lds16(Bt + (bn + row) * K + k0 + col, Bs + c * 8);
    }
    __syncthreads();
    #pragma unroll
    for (int ks = 0; ks < 2; ++ks) {
      bf16x8 af[4], bb[4];
      #pragma unroll
      for (int mt = 0; mt < 4; ++mt)
        af[mt] = *(const bf16x8*)(As + (wy * 64 + mt * 16 + l16) * 64 + ks * 32 + quad * 8);
      #pragma unroll
      for (int nt = 0; nt < 4; ++nt)
        bb[nt] = *(const bf16x8*)(Bs + (wx * 64 + nt * 16 + l16) * 64 + ks * 32 + quad * 8);
      #pragma unroll
      for (int mt = 0; mt < 4; ++mt)
        #pragma unroll
        for (int nt = 0; nt < 4; ++nt)
          acc[mt][nt] = __builtin_amdgcn_mfma_f32_16x16x32_bf16(af[mt], bb[nt], acc[mt][nt], 0, 0, 0);
    }
    __syncthreads();
  }
  #pragma unroll
  for (int mt = 0; mt < 4; ++mt)
    #pragma unroll
    for (int nt = 0; nt < 4; ++nt)
      #pragma unroll
      for (int r = 0; r < 4; ++r)
        C[(bm + wy * 64 + mt * 16 + quad * 4 + r) * N + bn + wx * 64 + nt * 16 + l16] =
            acc[mt][nt][r];
}

// exp2 + causal mask one 16-row strip of S^T; write bf16 P to swizzled LDS.
// No scalar l accumulation: l comes from an all-ones MFMA in the PV phase.
__device__ __forceinline__ void strip_exp_store(ushort_t* Ps, const f32x4* s, int kb,
                                                int sbase, int srowPs, int quad, int l16) {
  const bool masked = (kb + 63 > sbase);  // wave-uniform per strip
  #pragma unroll
  for (int nt = 0; nt < 4; ++nt) {
    float p[4];
    #pragma unroll
    for (int r = 0; r < 4; ++r) {
      float xv = s[nt][r];
      if (masked) {
        int kkg = kb + nt * 16 + quad * 4 + r;
        xv = (kkg <= sbase + l16) ? xv : -30000.f;
      }
      p[r] = fast_exp2(xv);  // raw v_exp_f32 (inputs bounded)
    }
    unsigned int u01, u23;
    asm("v_cvt_pk_bf16_f32 %0, %1, %2" : "=v"(u01) : "v"(p[0]), "v"(p[1]));
    asm("v_cvt_pk_bf16_f32 %0, %1, %2" : "=v"(u23) : "v"(p[2]), "v"(p[3]));
    uint2 pu; pu.x = u01; pu.y = u23;
    *(uint2*)(Ps + SWZ(srowPs, nt * 16 + quad * 4)) = pu;
  }
}

// Flash causal attention. 256 threads = 4 waves, each wave owns 32 q-rows
// (2 strips of 16); block covers 128 q-rows. grid (16 heads, 32); balanced
// pairing qt = y<16 ? 31-y : y-16. K/V double-buffered in swizzled LDS, ONE
// barrier per k-iter (R1 schedule). K frags read once/LDS-iter, reused for
// both strips. l via all-ones-A MFMA (contracts full k; no shuffle reduce).
__global__ __launch_bounds__(256, 3) void attn_fwd(const ushort_t* __restrict__ qkv,
                                                   const ushort_t* __restrict__ vT,
                                                   ushort_t* __restrict__ y) {
  __shared__ __attribute__((aligned(16))) ushort_t Ks[2][64 * 64];
  __shared__ __attribute__((aligned(16))) ushort_t Vt[2][64 * 64];
  __shared__ __attribute__((aligned(16))) ushort_t Ps[128 * 64];
  const int head = blockIdx.x;
  const int by = blockIdx.y;
  const int qt = (by < 16) ? (31 - by) : (by - 16);  // balanced CU pairing
  const int qb = qt * 128;
  const int ntiles = 2 * qt + 2;
  const int tid = threadIdx.x;
  const int lane = tid & 63, wave = tid >> 6;  // 4 waves
  const int quad = lane >> 4, l16 = lane & 15;
  const int hoff = head * 64;
  const int wrow = wave * 32;                   // wave's q-row base in tile
  const int ntw = 2 * qt + 1 + (wave >> 1);     // waves 0,1: last tile fully masked
  const int srow = tid >> 2, scol = (tid & 3) * 16;  // staging: 64 rows x 64 cols

  // Q fragments (B-operand), loaded once from global: bq[strip][ks]
  bf16x8 bq[2][2];
  #pragma unroll
  for (int st = 0; st < 2; ++st)
    #pragma unroll
    for (int ks = 0; ks < 2; ++ks)
      bq[st][ks] = *(const bf16x8*)(qkv + (size_t)(qb + wrow + st * 16 + l16) * 3072 +
                                    hoff + ks * 32 + quad * 8);

  // all-ones A-frag for the l row-sum MFMA
  bf16x8 ones;
  #pragma unroll
  for (int i = 0; i < 8; ++i) ones[i] = (__bf16)1.0f;

  // stage tile 0 into buf0 (reg roundtrip; swizzled ds_write)
  ushort8 kreg[2], vreg[2];
  #pragma unroll
  for (int i = 0; i < 2; ++i) {
    kreg[i] = *(const ushort8*)(qkv + (size_t)srow * 3072 + 1024 + hoff + scol + i * 8);
    vreg[i] = *(const ushort8*)(vT + (size_t)(hoff + srow) * 4096 + scol + i * 8);
  }
  #pragma unroll
  for (int i = 0; i < 2; ++i) {
    *(ushort8*)(Ks[0] + SWZ(srow, scol + i * 8)) = kreg[i];
    *(ushort8*)(Vt[0] + SWZ(srow, scol + i * 8)) = vreg[i];
  }
  // prefetch tile 1 regs (ntiles >= 2 always)
  #pragma unroll
  for (int i = 0; i < 2; ++i) {
    kreg[i] = *(const ushort8*)(qkv + (size_t)(64 + srow) * 3072 + 1024 + hoff + scol + i * 8);
    vreg[i] = *(const ushort8*)(vT + (size_t)(hoff + srow) * 4096 + 64 + scol + i * 8);
  }

  const f32x4 fzero = {0.f, 0.f, 0.f, 0.f};
  f32x4 o0[4], o1[4], ol0 = fzero, ol1 = fzero;
  #pragma unroll
  for (int nt = 0; nt < 4; ++nt) { o0[nt] = fzero; o1[nt] = fzero; }

  for (int t = 0; t < ntiles; ++t) {
    const int cur = t & 1;
    __syncthreads();  // buf[cur] writes visible; all waves done reading buf[1-cur]
    const bool active = (t < ntw);  // wave-uniform

    // S^T = K (Q*c)^T for both strips (K frags read once, reused)
    f32x4 s0[4], s1[4];
    if (active) {
      #pragma unroll
      for (int nt = 0; nt < 4; ++nt) { s0[nt] = fzero; s1[nt] = fzero; }
      __builtin_amdgcn_s_setprio(1);
      #pragma unroll
      for (int ks = 0; ks < 2; ++ks)
        #pragma unroll
        for (int nt = 0; nt < 4; ++nt) {
          bf16x8 ak = *(const bf16x8*)(Ks[cur] + SWZ(nt * 16 + l16, ks * 32 + quad * 8));
          s0[nt] = __builtin_amdgcn_mfma_f32_16x16x32_bf16(ak, bq[0][ks], s0[nt], 0, 0, 0);
          s1[nt] = __builtin_amdgcn_mfma_f32_16x16x32_bf16(ak, bq[1][ks], s1[nt], 0, 0, 0);
        }
      __builtin_amdgcn_s_setprio(0);
    }

    // stage tile t+1 into the other buffer; then issue loads for tile t+2
    if (t + 1 < ntiles) {
      #pragma unroll
      for (int i = 0; i < 2; ++i) {
        *(ushort8*)(Ks[1 - cur] + SWZ(srow, scol + i * 8)) = kreg[i];
        *(ushort8*)(Vt[1 - cur] + SWZ(srow, scol + i * 8)) = vreg[i];
      }
      if (t + 2 < ntiles) {
        const int kb2 = (t + 2) * 64;
        #pragma unroll
        for (int i = 0; i < 2; ++i) {
          kreg[i] = *(const ushort8*)(qkv + (size_t)(kb2 + srow) * 3072 + 1024 + hoff +
                                      scol + i * 8);
          vreg[i] = *(const ushort8*)(vT + (size_t)(hoff + srow) * 4096 + kb2 + scol + i * 8);
        }
      }
    }

    if (active) {
      // P = exp2(S^T) with causal mask -> wave-private swizzled LDS rows
      const int kb = t * 64;
      strip_exp_store(Ps, s0, kb, qb + wrow, wrow + l16, quad, l16);
      strip_exp_store(Ps, s1, kb, qb + wrow + 16, wrow + 16 + l16, quad, l16);

      // O^T += V^T P^T ; l += ones^T P^T (row-sum via MFMA)
      __builtin_amdgcn_s_setprio(1);
      #pragma unroll
      for (int ks = 0; ks < 2; ++ks) {
        bf16x8 bp0 = *(const bf16x8*)(Ps + SWZ(wrow + l16, ks * 32 + quad * 8));
        bf16x8 bp1 = *(const bf16x8*)(Ps + SWZ(wrow + 16 + l16, ks * 32 + quad * 8));
        #pragma unroll
        for (int nt = 0; nt < 4; ++nt) {
          bf16x8 av = *(const bf16x8*)(Vt[cur] + SWZ(nt * 16 + l16, ks * 32 + quad * 8));
          o0[nt] = __builtin_amdgcn_mfma_f32_16x16x32_bf16(av, bp0, o0[nt], 0, 0, 0);
          o1[nt] = __builtin_amdgcn_mfma_f32_16x16x32_bf16(av, bp1, o1[nt], 0, 0, 0);
        }
        ol0 = __builtin_amdgcn_mfma_f32_16x16x32_bf16(ones, bp0, ol0, 0, 0, 0);
        ol1 = __builtin_amdgcn_mfma_f32_16x16x32_bf16(ones, bp1, ol1, 0, 0, 0);
      }
      __builtin_amdgcn_s_setprio(0);
    }
  }

  // l[q=l16] is in every row-slot of ol; no cross-lane reduce needed.
  const float inv0 = 1.0f / ol0[0];
  const float inv1 = 1.0f / ol1[0];
  // o[nt][r] = O[q][d = nt*16+quad*4+r] -> packed stores
  #pragma unroll
  for (int nt = 0; nt < 4; ++nt) {
    ushort4v ov0, ov1;
    #pragma unroll
    for (int r = 0; r < 4; ++r) {
      ov0[r] = f2bf(o0[nt][r] * inv0);
      ov1[r] = f2bf(o1[nt][r] * inv1);
    }
    *(ushort4v*)(y + (size_t)(qb + wrow + l16) * 3072 + hoff + nt * 16 + quad * 4) = ov0;
    *(ushort4v*)(y + (size_t)(qb + wrow + 16 + l16) * 3072 + hoff + nt * 16 + quad * 4) = ov1;
  }
}

extern "C" void kernel_launch(void* const* d_in, const int* in_sizes, int n_in,
                              void* d_out, int out_size, void* d_ws, size_t ws_size,
                              hipStream_t stream) {
  const float* x = (const float*)d_in[0];       // [4096][1024] fp32
  const float* w_qkv = (const float*)d_in[1];   // [1024][3072] fp32
  const float* w_proj = (const float*)d_in[2];  // [1024][1024] fp32
  float* out = (float*)d_out;                   // [4096][1024] fp32

  ushort_t* ws = (ushort_t*)d_ws;
  ushort_t* qkv = ws;                            // [4096][3072]  [0, 24 MiB)
  ushort_t* wqkvT = ws + (size_t)4096 * 3072;    // [3072][1024]  [24, 30 MiB)
  ushort_t* vT = wqkvT;                          // [1024][4096]  [24, 32 MiB) alias after gemm1
  ushort_t* yb = qkv + 2048;                     // strided view into dead V cols (ld 3072)
  ushort_t* wprojT = wqkvT;                      // alias after attn
  ushort_t* xb = (ushort_t*)d_out;               // x bf16 scratch in d_out (dead before gemm2)

  cvt_f32_bf16<<<4096, 256, 0, stream>>>(x, xb);
  transpose_f32_bf16<<<dim3(96, 32), dim3(32, 8), 0, stream>>>(w_qkv, wqkvT, 1024, 3072);
  gemm_bt_bf16out<<<dim3(24, 32), 256, 0, stream>>>(xb, wqkvT, qkv, 4096, 3072, 1024);
  transpose_bf16_ld<<<dim3(32, 128), dim3(32, 8), 0, stream>>>(qkv + 2048, vT, 3072, 4096);
  attn_fwd<<<dim3(16, 32), 256, 0, stream>>>(qkv, vT, yb);
  transpose_f32_bf16<<<dim3(32, 32), dim3(32, 8), 0, stream>>>(w_proj, wprojT, 1024, 1024);
  gemm_bt_f32out<<<dim3(8, 32), 256, 0, stream>>>(yb, wprojT, out, 4096, 1024, 1024, 3072);
}

// Round 5
// 226.733 us; speedup vs baseline: 1.2645x; 1.1022x over previous
//
#include <hip/hip_runtime.h>
#include <hip/hip_bf16.h>

// Pipeline (bf16 internal, fp32 in/out):
//   cvt:    x fp32 -> xb bf16 (scratch in d_out, dead before gemm2 writes it)
//   transpose#1: w_qkv -> wqkvT bf16 [3072][1024]
//   gemm1:  qkv = xb @ wqkvT^T  (global_load_lds; Q cols scaled 0.125*log2e)
//   transpose_v: qkv V-cols -> vT bf16 [1024][4096]
//   attn:   flash causal. R4 post-mortem: VALU diet worked (VALUBusy 51->24)
//           but occupancy halved (12.8%) -> latency wall. R5: 64-row q-tiles,
//           grid (16 heads x 64) = 1024 blocks x 4 waves = 4096 waves, LDS
//           trimmed to EXACTLY 40960B -> 4 blocks/CU (160KiB), 16 waves/CU.
//           Balanced block->CU mapping: CU c (round-robin) gets by set
//           {r,r+16,r+32,r+48} -> qt {r,63-r,16+r,47-r}, sum 130 iters/CU.
//           Keeps R4 wins: XOR-swizzled LDS, dbuf K/V w/ reg prefetch, asm
//           v_exp_f32 + v_cvt_pk_bf16_f32, l via all-ones-A MFMA.
//   transpose#2 + gemm2 -> out fp32
// WS (32MiB): qkv [0,24M); wqkvT [24,30M); vT [24,32M) alias after gemm1;
//   yb strided into qkv's dead V cols; wprojT aliases wqkvT after attn.

typedef unsigned short ushort_t;
typedef __attribute__((ext_vector_type(8))) __bf16 bf16x8;
typedef __attribute__((ext_vector_type(8))) unsigned short ushort8;
typedef __attribute__((ext_vector_type(4))) unsigned short ushort4v;
typedef __attribute__((ext_vector_type(4))) float f32x4;

// Swizzled LDS addressing: row stride 64 elems (128B), XOR row bits into
// element bits 3..5 -> b64/b128 column walks hit distinct banks.
#define SWZ(row, e) (((row) << 6) + ((e) ^ (((row) & 7) << 3)))

__device__ inline unsigned short f2bf(float f) {
  union { float f; unsigned int u; } v;
  v.f = f;
  unsigned int r = v.u + 0x7fffu + ((v.u >> 16) & 1u);
  return (unsigned short)(r >> 16);
}

__device__ __forceinline__ float fast_exp2(float x) {
  float r;
  asm("v_exp_f32 %0, %1" : "=v"(r) : "v"(x));  // 2^x, inputs bounded by mask
  return r;
}

__device__ __forceinline__ void gl_lds16(const void* g, void* l) {
  __builtin_amdgcn_global_load_lds((const __attribute__((address_space(1))) void*)g,
                                   (__attribute__((address_space(3))) void*)l, 16, 0, 0);
}

// x fp32 -> bf16, 4 elems/thread
__global__ __launch_bounds__(256) void cvt_f32_bf16(const float* __restrict__ in,
                                                    ushort_t* __restrict__ out) {
  const size_t i = ((size_t)blockIdx.x * 256 + threadIdx.x) * 4;
  const float4 v = *(const float4*)(in + i);
  ushort4v o;
  o.x = f2bf(v.x); o.y = f2bf(v.y); o.z = f2bf(v.z); o.w = f2bf(v.w);
  *(ushort4v*)(out + i) = o;
}

// in fp32 [R][C] -> out bf16 [C][R]
__global__ __launch_bounds__(256) void transpose_f32_bf16(const float* __restrict__ in,
                                                          ushort_t* __restrict__ out,
                                                          int R, int C) {
  __shared__ ushort_t tile[32][33];
  const int r0 = blockIdx.y * 32, c0 = blockIdx.x * 32;
  const int tx = threadIdx.x, ty = threadIdx.y;  // block (32,8)
  #pragma unroll
  for (int j = 0; j < 32; j += 8)
    tile[ty + j][tx] = f2bf(in[(size_t)(r0 + ty + j) * C + c0 + tx]);
  __syncthreads();
  #pragma unroll
  for (int j = 0; j < 32; j += 8)
    out[(size_t)(c0 + ty + j) * R + r0 + tx] = tile[tx][ty + j];
}

// bf16 [rows, stride in_ld] -> bf16 [cols, stride out_ld]
__global__ __launch_bounds__(256) void transpose_bf16_ld(const ushort_t* __restrict__ in,
                                                         ushort_t* __restrict__ out,
                                                         int in_ld, int out_ld) {
  __shared__ ushort_t tile[32][33];
  const int r0 = blockIdx.y * 32, c0 = blockIdx.x * 32;
  const int tx = threadIdx.x, ty = threadIdx.y;
  #pragma unroll
  for (int j = 0; j < 32; j += 8)
    tile[ty + j][tx] = in[(size_t)(r0 + ty + j) * in_ld + c0 + tx];
  __syncthreads();
  #pragma unroll
  for (int j = 0; j < 32; j += 8)
    out[(size_t)(c0 + ty + j) * out_ld + r0 + tx] = tile[tx][ty + j];
}

// C bf16 = A(bf16) @ Bt^T, both staged async. Q-scale on blockIdx.x<8 (cols<1024).
__global__ __launch_bounds__(256) void gemm_bt_bf16out(const ushort_t* __restrict__ A,
                                                       const ushort_t* __restrict__ Bt,
                                                       ushort_t* __restrict__ C,
                                                       int M, int N, int K) {
  __shared__ __attribute__((aligned(16))) ushort_t As[128 * 64];
  __shared__ __attribute__((aligned(16))) ushort_t Bs[128 * 64];
  const int tid = threadIdx.x;
  const int lane = tid & 63;
  const int wave = tid >> 6;
  const int wy = wave >> 1, wx = wave & 1;
  const int quad = lane >> 4, l16 = lane & 15;
  const size_t bm = (size_t)blockIdx.y * 128;
  const size_t bn = (size_t)blockIdx.x * 128;

  const f32x4 fzero = {0.f, 0.f, 0.f, 0.f};
  f32x4 acc[4][4];
  #pragma unroll
  for (int i = 0; i < 4; ++i)
    #pragma unroll
    for (int j = 0; j < 4; ++j) acc[i][j] = fzero;

  for (int k0 = 0; k0 < K; k0 += 64) {
    #pragma unroll
    for (int i = 0; i < 4; ++i) {
      int c = (wave * 4 + i) * 64 + lane;
      int row = c >> 3, col = (c & 7) * 8;
      gl_lds16(A + (bm + row) * K + k0 + col, As + c * 8);
      gl_lds16(Bt + (bn + row) * K + k0 + col, Bs + c * 8);
    }
    __syncthreads();
    #pragma unroll
    for (int ks = 0; ks < 2; ++ks) {
      bf16x8 af[4], bb[4];
      #pragma unroll
      for (int mt = 0; mt < 4; ++mt)
        af[mt] = *(const bf16x8*)(As + (wy * 64 + mt * 16 + l16) * 64 + ks * 32 + quad * 8);
      #pragma unroll
      for (int nt = 0; nt < 4; ++nt)
        bb[nt] = *(const bf16x8*)(Bs + (wx * 64 + nt * 16 + l16) * 64 + ks * 32 + quad * 8);
      #pragma unroll
      for (int mt = 0; mt < 4; ++mt)
        #pragma unroll
        for (int nt = 0; nt < 4; ++nt)
          acc[mt][nt] = __builtin_amdgcn_mfma_f32_16x16x32_bf16(af[mt], bb[nt], acc[mt][nt], 0, 0, 0);
    }
    __syncthreads();
  }
  const float sc = (blockIdx.x < 8) ? 0.18033688f : 1.0f;  // 0.125*log2(e) for Q cols
  #pragma unroll
  for (int mt = 0; mt < 4; ++mt)
    #pragma unroll
    for (int nt = 0; nt < 4; ++nt)
      #pragma unroll
      for (int r = 0; r < 4; ++r)
        C[(bm + wy * 64 + mt * 16 + quad * 4 + r) * N + bn + wx * 64 + nt * 16 + l16] =
            f2bf(acc[mt][nt][r] * sc);
}

// A bf16 [M][K] row stride lda, Bt bf16 [N][K], C fp32. Both async.
__global__ __launch_bounds__(256) void gemm_bt_f32out(const ushort_t* __restrict__ A,
                                                      const ushort_t* __restrict__ Bt,
                                                      float* __restrict__ C,
                                                      int M, int N, int K, int lda) {
  __shared__ __attribute__((aligned(16))) ushort_t As[128 * 64];
  __shared__ __attribute__((aligned(16))) ushort_t Bs[128 * 64];
  const int tid = threadIdx.x;
  const int lane = tid & 63;
  const int wave = tid >> 6;
  const int wy = wave >> 1, wx = wave & 1;
  const int quad = lane >> 4, l16 = lane & 15;
  const size_t bm = (size_t)blockIdx.y * 128;
  const size_t bn = (size_t)blockIdx.x * 128;

  const f32x4 fzero = {0.f, 0.f, 0.f, 0.f};
  f32x4 acc[4][4];
  #pragma unroll
  for (int i = 0; i < 4; ++i)
    #pragma unroll
    for (int j = 0; j < 4; ++j) acc[i][j] = fzero;

  for (int k0 = 0; k0 < K; k0 += 64) {
    #pragma unroll
    for (int i = 0; i < 4; ++i) {
      int c = (wave * 4 + i) * 64 + lane;
      int row = c >> 3, col = (c & 7) * 8;
      gl_lds16(A + (bm + row) * lda + k0 + col, As + c * 8);
      gl_lds16(Bt + (bn + row) * K + k0 + col, Bs + c * 8);
    }
    __syncthreads();
    #pragma unroll
    for (int ks = 0; ks < 2; ++ks) {
      bf16x8 af[4], bb[4];
      #pragma unroll
      for (int mt = 0; mt < 4; ++mt)
        af[mt] = *(const bf16x8*)(As + (wy * 64 + mt * 16 + l16) * 64 + ks * 32 + quad * 8);
      #pragma unroll
      for (int nt = 0; nt < 4; ++nt)
        bb[nt] = *(const bf16x8*)(Bs + (wx * 64 + nt * 16 + l16) * 64 + ks * 32 + quad * 8);
      #pragma unroll
      for (int mt = 0; mt < 4; ++mt)
        #pragma unroll
        for (int nt = 0; nt < 4; ++nt)
          acc[mt][nt] = __builtin_amdgcn_mfma_f32_16x16x32_bf16(af[mt], bb[nt], acc[mt][nt], 0, 0, 0);
    }
    __syncthreads();
  }
  #pragma unroll
  for (int mt = 0; mt < 4; ++mt)
    #pragma unroll
    for (int nt = 0; nt < 4; ++nt)
      #pragma unroll
      for (int r = 0; r < 4; ++r)
        C[(bm + wy * 64 + mt * 16 + quad * 4 + r) * N + bn + wx * 64 + nt * 16 + l16] =
            acc[mt][nt][r];
}

// exp2 + causal mask one 16-row strip of S^T; write bf16 P to swizzled LDS.
// No scalar l accumulation: l comes from an all-ones MFMA in the PV phase.
__device__ __forceinline__ void strip_exp_store(ushort_t* Ps, const f32x4* s, int kb,
                                                int sbase, int srowPs, int quad, int l16) {
  const bool masked = (kb + 63 > sbase);  // wave-uniform per strip
  #pragma unroll
  for (int nt = 0; nt < 4; ++nt) {
    float p[4];
    #pragma unroll
    for (int r = 0; r < 4; ++r) {
      float xv = s[nt][r];
      if (masked) {
        int kkg = kb + nt * 16 + quad * 4 + r;
        xv = (kkg <= sbase + l16) ? xv : -30000.f;
      }
      p[r] = fast_exp2(xv);  // raw v_exp_f32 (inputs bounded)
    }
    unsigned int u01, u23;
    asm("v_cvt_pk_bf16_f32 %0, %1, %2" : "=v"(u01) : "v"(p[0]), "v"(p[1]));
    asm("v_cvt_pk_bf16_f32 %0, %1, %2" : "=v"(u23) : "v"(p[2]), "v"(p[3]));
    uint2 pu; pu.x = u01; pu.y = u23;
    *(uint2*)(Ps + SWZ(srowPs, nt * 16 + quad * 4)) = pu;
  }
}

// Flash causal attention. 64-row q-tile per block, 256 threads = 4 waves,
// each wave owns 16 q-rows. grid (16 heads, 64) = 1024 blocks, LDS 40960B
// -> 4 blocks/CU (160KiB exactly), 16 waves/CU. Balanced qt mapping: under
// round-robin block->CU, CU gets by set {r,r+16,r+32,r+48}; map to qt
// {r, 63-r, 16+r, 47-r} so every CU sums to 130 tile-iters.
// K/V double-buffered in swizzled LDS, ONE barrier per k-iter; reg prefetch
// of tile t+2 lands during compute. l via all-ones-A MFMA (no shuffle).
__global__ __launch_bounds__(256, 4) void attn_fwd(const ushort_t* __restrict__ qkv,
                                                   const ushort_t* __restrict__ vT,
                                                   ushort_t* __restrict__ y) {
  __shared__ __attribute__((aligned(16))) ushort_t Ks[2][64 * 64];
  __shared__ __attribute__((aligned(16))) ushort_t Vt[2][64 * 64];
  __shared__ __attribute__((aligned(16))) ushort_t Ps[64 * 64];
  const int head = blockIdx.x;
  const int by = blockIdx.y;
  const int g = by >> 4, r4 = by & 15;  // balanced per-CU 4-set mapping
  const int qt = (g == 0) ? r4 : (g == 1) ? (63 - r4) : (g == 2) ? (16 + r4) : (47 - r4);
  const int qb = qt * 64;
  const int ntiles = qt + 1;
  const int tid = threadIdx.x;
  const int lane = tid & 63, wave = tid >> 6;  // 4 waves
  const int quad = lane >> 4, l16 = lane & 15;
  const int hoff = head * 64;
  const int wrow = wave * 16;                        // wave's q-row base in tile
  const int srow = tid >> 2, scol = (tid & 3) * 16;  // staging: 64 rows x 64 cols

  // Q fragments (B-operand), loaded once from global: bq[ks]
  bf16x8 bq[2];
  #pragma unroll
  for (int ks = 0; ks < 2; ++ks)
    bq[ks] = *(const bf16x8*)(qkv + (size_t)(qb + wrow + l16) * 3072 + hoff +
                              ks * 32 + quad * 8);

  // all-ones A-frag for the l row-sum MFMA
  bf16x8 ones;
  #pragma unroll
  for (int i = 0; i < 8; ++i) ones[i] = (__bf16)1.0f;

  // stage tile 0 into buf0 (reg roundtrip; swizzled ds_write)
  ushort8 kreg[2], vreg[2];
  #pragma unroll
  for (int i = 0; i < 2; ++i) {
    kreg[i] = *(const ushort8*)(qkv + (size_t)srow * 3072 + 1024 + hoff + scol + i * 8);
    vreg[i] = *(const ushort8*)(vT + (size_t)(hoff + srow) * 4096 + scol + i * 8);
  }
  #pragma unroll
  for (int i = 0; i < 2; ++i) {
    *(ushort8*)(Ks[0] + SWZ(srow, scol + i * 8)) = kreg[i];
    *(ushort8*)(Vt[0] + SWZ(srow, scol + i * 8)) = vreg[i];
  }
  // prefetch tile 1 regs (in-bounds even when unused: rows 64..127 < 4096)
  #pragma unroll
  for (int i = 0; i < 2; ++i) {
    kreg[i] = *(const ushort8*)(qkv + (size_t)(64 + srow) * 3072 + 1024 + hoff + scol + i * 8);
    vreg[i] = *(const ushort8*)(vT + (size_t)(hoff + srow) * 4096 + 64 + scol + i * 8);
  }

  const f32x4 fzero = {0.f, 0.f, 0.f, 0.f};
  f32x4 o0[4], ol0 = fzero;
  #pragma unroll
  for (int nt = 0; nt < 4; ++nt) o0[nt] = fzero;

  for (int t = 0; t < ntiles; ++t) {
    const int cur = t & 1;
    __syncthreads();  // buf[cur] writes visible; all waves done reading buf[1-cur]

    // S^T = K (Q*c)^T : row = kk_local = quad*4+r, col = q_local = l16
    f32x4 s0[4];
    #pragma unroll
    for (int nt = 0; nt < 4; ++nt) s0[nt] = fzero;
    __builtin_amdgcn_s_setprio(1);
    #pragma unroll
    for (int ks = 0; ks < 2; ++ks)
      #pragma unroll
      for (int nt = 0; nt < 4; ++nt) {
        bf16x8 ak = *(const bf16x8*)(Ks[cur] + SWZ(nt * 16 + l16, ks * 32 + quad * 8));
        s0[nt] = __builtin_amdgcn_mfma_f32_16x16x32_bf16(ak, bq[ks], s0[nt], 0, 0, 0);
      }
    __builtin_amdgcn_s_setprio(0);

    // stage tile t+1 into the other buffer; then issue loads for tile t+2
    if (t + 1 < ntiles) {
      #pragma unroll
      for (int i = 0; i < 2; ++i) {
        *(ushort8*)(Ks[1 - cur] + SWZ(srow, scol + i * 8)) = kreg[i];
        *(ushort8*)(Vt[1 - cur] + SWZ(srow, scol + i * 8)) = vreg[i];
      }
      if (t + 2 < ntiles) {
        const int kb2 = (t + 2) * 64;
        #pragma unroll
        for (int i = 0; i < 2; ++i) {
          kreg[i] = *(const ushort8*)(qkv + (size_t)(kb2 + srow) * 3072 + 1024 + hoff +
                                      scol + i * 8);
          vreg[i] = *(const ushort8*)(vT + (size_t)(hoff + srow) * 4096 + kb2 + scol + i * 8);
        }
      }
    }

    // P = exp2(S^T) with causal mask -> wave-private swizzled LDS rows
    const int kb = t * 64;
    strip_exp_store(Ps, s0, kb, qb + wrow, wrow + l16, quad, l16);

    // O^T += V^T P^T ; l += ones^T P^T (row-sum via MFMA)
    __builtin_amdgcn_s_setprio(1);
    #pragma unroll
    for (int ks = 0; ks < 2; ++ks) {
      bf16x8 bp0 = *(const bf16x8*)(Ps + SWZ(wrow + l16, ks * 32 + quad * 8));
      #pragma unroll
      for (int nt = 0; nt < 4; ++nt) {
        bf16x8 av = *(const bf16x8*)(Vt[cur] + SWZ(nt * 16 + l16, ks * 32 + quad * 8));
        o0[nt] = __builtin_amdgcn_mfma_f32_16x16x32_bf16(av, bp0, o0[nt], 0, 0, 0);
      }
      ol0 = __builtin_amdgcn_mfma_f32_16x16x32_bf16(ones, bp0, ol0, 0, 0, 0);
    }
    __builtin_amdgcn_s_setprio(0);
  }

  // l[q=l16] is in every row-slot of ol0; no cross-lane reduce needed.
  const float inv0 = 1.0f / ol0[0];
  // o0[nt][r] = O[q = qb+wrow+l16][d = nt*16+quad*4+r] -> packed stores
  #pragma unroll
  for (int nt = 0; nt < 4; ++nt) {
    ushort4v ov0;
    #pragma unroll
    for (int r = 0; r < 4; ++r) ov0[r] = f2bf(o0[nt][r] * inv0);
    *(ushort4v*)(y + (size_t)(qb + wrow + l16) * 3072 + hoff + nt * 16 + quad * 4) = ov0;
  }
}

extern "C" void kernel_launch(void* const* d_in, const int* in_sizes, int n_in,
                              void* d_out, int out_size, void* d_ws, size_t ws_size,
                              hipStream_t stream) {
  const float* x = (const float*)d_in[0];       // [4096][1024] fp32
  const float* w_qkv = (const float*)d_in[1];   // [1024][3072] fp32
  const float* w_proj = (const float*)d_in[2];  // [1024][1024] fp32
  float* out = (float*)d_out;                   // [4096][1024] fp32

  ushort_t* ws = (ushort_t*)d_ws;
  ushort_t* qkv = ws;                            // [4096][3072]  [0, 24 MiB)
  ushort_t* wqkvT = ws + (size_t)4096 * 3072;    // [3072][1024]  [24, 30 MiB)
  ushort_t* vT = wqkvT;                          // [1024][4096]  [24, 32 MiB) alias after gemm1
  ushort_t* yb = qkv + 2048;                     // strided view into dead V cols (ld 3072)
  ushort_t* wprojT = wqkvT;                      // alias after attn
  ushort_t* xb = (ushort_t*)d_out;               // x bf16 scratch in d_out (dead before gemm2)

  cvt_f32_bf16<<<4096, 256, 0, stream>>>(x, xb);
  transpose_f32_bf16<<<dim3(96, 32), dim3(32, 8), 0, stream>>>(w_qkv, wqkvT, 1024, 3072);
  gemm_bt_bf16out<<<dim3(24, 32), 256, 0, stream>>>(xb, wqkvT, qkv, 4096, 3072, 1024);
  transpose_bf16_ld<<<dim3(32, 128), dim3(32, 8), 0, stream>>>(qkv + 2048, vT, 3072, 4096);
  attn_fwd<<<dim3(16, 64), 256, 0, stream>>>(qkv, vT, yb);
  transpose_f32_bf16<<<dim3(32, 32), dim3(32, 8), 0, stream>>>(w_proj, wprojT, 1024, 1024);
  gemm_bt_f32out<<<dim3(8, 32), 256, 0, stream>>>(yb, wprojT, out, 4096, 1024, 1024, 3072);
}

// Round 6
// 216.348 us; speedup vs baseline: 1.3252x; 1.0480x over previous
//
#include <hip/hip_runtime.h>
#include <hip/hip_bf16.h>

// Pipeline (bf16 internal, fp32 in/out):
//   cvt:    x fp32 -> xb bf16 (scratch in d_out[0,8M), dead before gemm2 writes)
//   transpose#1: w_qkv -> wqkvT bf16 [3072][1024]
//   gemm1:  qkv = xb @ wqkvT^T  (global_load_lds; Q cols scaled 0.125*log2e).
//           V-col blocks (bx>=16) write DIRECTLY TRANSPOSED to vT via LDS
//           bounce (kills the transpose_v kernel + its 24MB round-trip);
//           their qkv C-write is skipped (V cols dead, later host yb).
//   attn:   flash causal (R5 structure, frozen): 64-row q-tile, 4 waves,
//           grid (16x64), balanced per-CU 4-set qt map, 40KiB LDS ->
//           4 blocks/CU, dbuf K/V swizzled, asm exp2/cvt_pk, ones-MFMA l.
//   transpose#2 + gemm2 -> out fp32. gemm2 retiled 128x64 -> 512 blocks
//           (2/CU vs 1/CU at 128x128: barriers now overlap across blocks).
// WS (32MiB): qkv [0,24M); wqkvT [24,30M); wprojT aliases wqkvT after gemm1.
// d_out (16MiB): xb bf16 [0,8M) (dead before gemm2 writes out);
//                vT [1024][4096] bf16 [8M,16M) (dead after attn).
// yb strided into qkv's dead V cols (ld 3072).

typedef unsigned short ushort_t;
typedef __attribute__((ext_vector_type(8))) __bf16 bf16x8;
typedef __attribute__((ext_vector_type(8))) unsigned short ushort8;
typedef __attribute__((ext_vector_type(4))) unsigned short ushort4v;
typedef __attribute__((ext_vector_type(2))) unsigned short ushort2v;
typedef __attribute__((ext_vector_type(4))) float f32x4;

// Swizzled LDS addressing: row stride 64 elems (128B), XOR row bits into
// element bits 3..5 -> b64/b128 column walks hit distinct banks.
#define SWZ(row, e) (((row) << 6) + ((e) ^ (((row) & 7) << 3)))

__device__ inline unsigned short f2bf(float f) {
  union { float f; unsigned int u; } v;
  v.f = f;
  unsigned int r = v.u + 0x7fffu + ((v.u >> 16) & 1u);
  return (unsigned short)(r >> 16);
}

__device__ __forceinline__ float fast_exp2(float x) {
  float r;
  asm("v_exp_f32 %0, %1" : "=v"(r) : "v"(x));  // 2^x, inputs bounded by mask
  return r;
}

__device__ __forceinline__ void gl_lds16(const void* g, void* l) {
  __builtin_amdgcn_global_load_lds((const __attribute__((address_space(1))) void*)g,
                                   (__attribute__((address_space(3))) void*)l, 16, 0, 0);
}

// x fp32 -> bf16, 4 elems/thread
__global__ __launch_bounds__(256) void cvt_f32_bf16(const float* __restrict__ in,
                                                    ushort_t* __restrict__ out) {
  const size_t i = ((size_t)blockIdx.x * 256 + threadIdx.x) * 4;
  const float4 v = *(const float4*)(in + i);
  ushort4v o;
  o.x = f2bf(v.x); o.y = f2bf(v.y); o.z = f2bf(v.z); o.w = f2bf(v.w);
  *(ushort4v*)(out + i) = o;
}

// in fp32 [R][C] -> out bf16 [C][R]
__global__ __launch_bounds__(256) void transpose_f32_bf16(const float* __restrict__ in,
                                                          ushort_t* __restrict__ out,
                                                          int R, int C) {
  __shared__ ushort_t tile[32][33];
  const int r0 = blockIdx.y * 32, c0 = blockIdx.x * 32;
  const int tx = threadIdx.x, ty = threadIdx.y;  // block (32,8)
  #pragma unroll
  for (int j = 0; j < 32; j += 8)
    tile[ty + j][tx] = f2bf(in[(size_t)(r0 + ty + j) * C + c0 + tx]);
  __syncthreads();
  #pragma unroll
  for (int j = 0; j < 32; j += 8)
    out[(size_t)(c0 + ty + j) * R + r0 + tx] = tile[tx][ty + j];
}

// C bf16 = A(bf16) @ Bt^T, both staged async. Q-scale on blockIdx.x<8.
// blockIdx.x>=16 (V cols): write transposed to vT[col-2048][row] via LDS
// bounce instead of C (transpose_v fusion).
__global__ __launch_bounds__(256) void gemm_bt_bf16out(const ushort_t* __restrict__ A,
                                                       const ushort_t* __restrict__ Bt,
                                                       ushort_t* __restrict__ C,
                                                       ushort_t* __restrict__ vT,
                                                       int M, int N, int K) {
  __shared__ __attribute__((aligned(16))) ushort_t smem[128 * 64 * 2];
  ushort_t* As = smem;
  ushort_t* Bs = smem + 128 * 64;
  const int tid = threadIdx.x;
  const int lane = tid & 63;
  const int wave = tid >> 6;
  const int wy = wave >> 1, wx = wave & 1;
  const int quad = lane >> 4, l16 = lane & 15;
  const size_t bm = (size_t)blockIdx.y * 128;
  const size_t bn = (size_t)blockIdx.x * 128;

  const f32x4 fzero = {0.f, 0.f, 0.f, 0.f};
  f32x4 acc[4][4];
  #pragma unroll
  for (int i = 0; i < 4; ++i)
    #pragma unroll
    for (int j = 0; j < 4; ++j) acc[i][j] = fzero;

  for (int k0 = 0; k0 < K; k0 += 64) {
    #pragma unroll
    for (int i = 0; i < 4; ++i) {
      int c = (wave * 4 + i) * 64 + lane;
      int row = c >> 3, col = (c & 7) * 8;
      gl_lds16(A + (bm + row) * K + k0 + col, As + c * 8);
      gl_lds16(Bt + (bn + row) * K + k0 + col, Bs + c * 8);
    }
    __syncthreads();
    #pragma unroll
    for (int ks = 0; ks < 2; ++ks) {
      bf16x8 af[4], bb[4];
      #pragma unroll
      for (int mt = 0; mt < 4; ++mt)
        af[mt] = *(const bf16x8*)(As + (wy * 64 + mt * 16 + l16) * 64 + ks * 32 + quad * 8);
      #pragma unroll
      for (int nt = 0; nt < 4; ++nt)
        bb[nt] = *(const bf16x8*)(Bs + (wx * 64 + nt * 16 + l16) * 64 + ks * 32 + quad * 8);
      #pragma unroll
      for (int mt = 0; mt < 4; ++mt)
        #pragma unroll
        for (int nt = 0; nt < 4; ++nt)
          acc[mt][nt] = __builtin_amdgcn_mfma_f32_16x16x32_bf16(af[mt], bb[nt], acc[mt][nt], 0, 0, 0);
    }
    __syncthreads();
  }

  if (blockIdx.x < 16) {
    // Q/K cols: normal C write (Q scaled)
    const float sc = (blockIdx.x < 8) ? 0.18033688f : 1.0f;  // 0.125*log2(e)
    #pragma unroll
    for (int mt = 0; mt < 4; ++mt)
      #pragma unroll
      for (int nt = 0; nt < 4; ++nt)
        #pragma unroll
        for (int r = 0; r < 4; ++r)
          C[(bm + wy * 64 + mt * 16 + quad * 4 + r) * N + bn + wx * 64 + nt * 16 + l16] =
              f2bf(acc[mt][nt][r] * sc);
  } else {
    // V cols: transpose via LDS bounce (two 64-col passes), store to vT.
    // T layout: [v_local 0..63][row_local 0..127], pitch 136 (b128-aligned,
    // 272B row stride -> <=2-way banks on write).
    const int vbase = (int)bn - 2048;
    #pragma unroll
    for (int p = 0; p < 2; ++p) {
      if (wx == p) {
        #pragma unroll
        for (int nt = 0; nt < 4; ++nt)
          #pragma unroll
          for (int mt = 0; mt < 4; ++mt)
            #pragma unroll
            for (int i = 0; i < 2; ++i) {
              ushort2v pr;
              pr.x = f2bf(acc[mt][nt][2 * i]);
              pr.y = f2bf(acc[mt][nt][2 * i + 1]);
              *(ushort2v*)(smem + (nt * 16 + l16) * 136 + wy * 64 + mt * 16 + quad * 4 +
                           2 * i) = pr;
            }
      }
      __syncthreads();
      #pragma unroll
      for (int j = 0; j < 4; ++j) {
        int v = (tid >> 4) + j * 16;
        int row0 = (tid & 15) * 8;
        ushort8 val = *(const ushort8*)(smem + v * 136 + row0);
        *(ushort8*)(vT + (size_t)(vbase + p * 64 + v) * 4096 + bm + row0) = val;
      }
      __syncthreads();
    }
  }
}

// A bf16 [M][K] row stride lda, Bt bf16 [N][K], C fp32. 128x64 tile ->
// grid (N/64, M/128) = 512 blocks, 2 blocks/CU (was 1/CU at 128x128:
// nothing to overlap barrier stalls against).
__global__ __launch_bounds__(256) void gemm_bt_f32out(const ushort_t* __restrict__ A,
                                                      const ushort_t* __restrict__ Bt,
                                                      float* __restrict__ C,
                                                      int M, int N, int K, int lda) {
  __shared__ __attribute__((aligned(16))) ushort_t As[128 * 64];
  __shared__ __attribute__((aligned(16))) ushort_t Bs[64 * 64];
  const int tid = threadIdx.x;
  const int lane = tid & 63;
  const int wave = tid >> 6;
  const int wy = wave >> 1, wx = wave & 1;  // wave tile: 64 rows x 32 cols
  const int quad = lane >> 4, l16 = lane & 15;
  const size_t bm = (size_t)blockIdx.y * 128;
  const size_t bn = (size_t)blockIdx.x * 64;

  const f32x4 fzero = {0.f, 0.f, 0.f, 0.f};
  f32x4 acc[4][2];
  #pragma unroll
  for (int i = 0; i < 4; ++i)
    #pragma unroll
    for (int j = 0; j < 2; ++j) acc[i][j] = fzero;

  for (int k0 = 0; k0 < K; k0 += 64) {
    #pragma unroll
    for (int i = 0; i < 4; ++i) {
      int c = (wave * 4 + i) * 64 + lane;
      int row = c >> 3, col = (c & 7) * 8;
      gl_lds16(A + (bm + row) * lda + k0 + col, As + c * 8);
    }
    #pragma unroll
    for (int i = 0; i < 2; ++i) {
      int c = (wave * 2 + i) * 64 + lane;
      int row = c >> 3, col = (c & 7) * 8;
      gl_lds16(Bt + (bn + row) * K + k0 + col, Bs + c * 8);
    }
    __syncthreads();
    #pragma unroll
    for (int ks = 0; ks < 2; ++ks) {
      bf16x8 af[4], bb[2];
      #pragma unroll
      for (int mt = 0; mt < 4; ++mt)
        af[mt] = *(const bf16x8*)(As + (wy * 64 + mt * 16 + l16) * 64 + ks * 32 + quad * 8);
      #pragma unroll
      for (int nt = 0; nt < 2; ++nt)
        bb[nt] = *(const bf16x8*)(Bs + (wx * 32 + nt * 16 + l16) * 64 + ks * 32 + quad * 8);
      #pragma unroll
      for (int mt = 0; mt < 4; ++mt)
        #pragma unroll
        for (int nt = 0; nt < 2; ++nt)
          acc[mt][nt] = __builtin_amdgcn_mfma_f32_16x16x32_bf16(af[mt], bb[nt], acc[mt][nt], 0, 0, 0);
    }
    __syncthreads();
  }
  #pragma unroll
  for (int mt = 0; mt < 4; ++mt)
    #pragma unroll
    for (int nt = 0; nt < 2; ++nt)
      #pragma unroll
      for (int r = 0; r < 4; ++r)
        C[(bm + wy * 64 + mt * 16 + quad * 4 + r) * N + bn + wx * 32 + nt * 16 + l16] =
            acc[mt][nt][r];
}

// exp2 + causal mask one 16-row strip of S^T; write bf16 P to swizzled LDS.
// No scalar l accumulation: l comes from an all-ones MFMA in the PV phase.
__device__ __forceinline__ void strip_exp_store(ushort_t* Ps, const f32x4* s, int kb,
                                                int sbase, int srowPs, int quad, int l16) {
  const bool masked = (kb + 63 > sbase);  // wave-uniform per strip
  #pragma unroll
  for (int nt = 0; nt < 4; ++nt) {
    float p[4];
    #pragma unroll
    for (int r = 0; r < 4; ++r) {
      float xv = s[nt][r];
      if (masked) {
        int kkg = kb + nt * 16 + quad * 4 + r;
        xv = (kkg <= sbase + l16) ? xv : -30000.f;
      }
      p[r] = fast_exp2(xv);  // raw v_exp_f32 (inputs bounded)
    }
    unsigned int u01, u23;
    asm("v_cvt_pk_bf16_f32 %0, %1, %2" : "=v"(u01) : "v"(p[0]), "v"(p[1]));
    asm("v_cvt_pk_bf16_f32 %0, %1, %2" : "=v"(u23) : "v"(p[2]), "v"(p[3]));
    uint2 pu; pu.x = u01; pu.y = u23;
    *(uint2*)(Ps + SWZ(srowPs, nt * 16 + quad * 4)) = pu;
  }
}

// Flash causal attention. 64-row q-tile per block, 256 threads = 4 waves,
// each wave owns 16 q-rows. grid (16 heads, 64) = 1024 blocks, LDS 40960B
// -> 4 blocks/CU (160KiB exactly), 16 waves/CU. Balanced qt mapping: under
// round-robin block->CU, CU gets by set {r,r+16,r+32,r+48}; map to qt
// {r, 63-r, 16+r, 47-r} so every CU sums to 130 tile-iters.
// K/V double-buffered in swizzled LDS, ONE barrier per k-iter; reg prefetch
// of tile t+2 lands during compute. l via all-ones-A MFMA (no shuffle).
__global__ __launch_bounds__(256, 4) void attn_fwd(const ushort_t* __restrict__ qkv,
                                                   const ushort_t* __restrict__ vT,
                                                   ushort_t* __restrict__ y) {
  __shared__ __attribute__((aligned(16))) ushort_t Ks[2][64 * 64];
  __shared__ __attribute__((aligned(16))) ushort_t Vt[2][64 * 64];
  __shared__ __attribute__((aligned(16))) ushort_t Ps[64 * 64];
  const int head = blockIdx.x;
  const int by = blockIdx.y;
  const int g = by >> 4, r4 = by & 15;  // balanced per-CU 4-set mapping
  const int qt = (g == 0) ? r4 : (g == 1) ? (63 - r4) : (g == 2) ? (16 + r4) : (47 - r4);
  const int qb = qt * 64;
  const int ntiles = qt + 1;
  const int tid = threadIdx.x;
  const int lane = tid & 63, wave = tid >> 6;  // 4 waves
  const int quad = lane >> 4, l16 = lane & 15;
  const int hoff = head * 64;
  const int wrow = wave * 16;                        // wave's q-row base in tile
  const int srow = tid >> 2, scol = (tid & 3) * 16;  // staging: 64 rows x 64 cols

  // Q fragments (B-operand), loaded once from global: bq[ks]
  bf16x8 bq[2];
  #pragma unroll
  for (int ks = 0; ks < 2; ++ks)
    bq[ks] = *(const bf16x8*)(qkv + (size_t)(qb + wrow + l16) * 3072 + hoff +
                              ks * 32 + quad * 8);

  // all-ones A-frag for the l row-sum MFMA
  bf16x8 ones;
  #pragma unroll
  for (int i = 0; i < 8; ++i) ones[i] = (__bf16)1.0f;

  // stage tile 0 into buf0 (reg roundtrip; swizzled ds_write)
  ushort8 kreg[2], vreg[2];
  #pragma unroll
  for (int i = 0; i < 2; ++i) {
    kreg[i] = *(const ushort8*)(qkv + (size_t)srow * 3072 + 1024 + hoff + scol + i * 8);
    vreg[i] = *(const ushort8*)(vT + (size_t)(hoff + srow) * 4096 + scol + i * 8);
  }
  #pragma unroll
  for (int i = 0; i < 2; ++i) {
    *(ushort8*)(Ks[0] + SWZ(srow, scol + i * 8)) = kreg[i];
    *(ushort8*)(Vt[0] + SWZ(srow, scol + i * 8)) = vreg[i];
  }
  // prefetch tile 1 regs (in-bounds even when unused: rows 64..127 < 4096)
  #pragma unroll
  for (int i = 0; i < 2; ++i) {
    kreg[i] = *(const ushort8*)(qkv + (size_t)(64 + srow) * 3072 + 1024 + hoff + scol + i * 8);
    vreg[i] = *(const ushort8*)(vT + (size_t)(hoff + srow) * 4096 + 64 + scol + i * 8);
  }

  const f32x4 fzero = {0.f, 0.f, 0.f, 0.f};
  f32x4 o0[4], ol0 = fzero;
  #pragma unroll
  for (int nt = 0; nt < 4; ++nt) o0[nt] = fzero;

  for (int t = 0; t < ntiles; ++t) {
    const int cur = t & 1;
    __syncthreads();  // buf[cur] writes visible; all waves done reading buf[1-cur]

    // S^T = K (Q*c)^T : row = kk_local = quad*4+r, col = q_local = l16
    f32x4 s0[4];
    #pragma unroll
    for (int nt = 0; nt < 4; ++nt) s0[nt] = fzero;
    __builtin_amdgcn_s_setprio(1);
    #pragma unroll
    for (int ks = 0; ks < 2; ++ks)
      #pragma unroll
      for (int nt = 0; nt < 4; ++nt) {
        bf16x8 ak = *(const bf16x8*)(Ks[cur] + SWZ(nt * 16 + l16, ks * 32 + quad * 8));
        s0[nt] = __builtin_amdgcn_mfma_f32_16x16x32_bf16(ak, bq[ks], s0[nt], 0, 0, 0);
      }
    __builtin_amdgcn_s_setprio(0);

    // stage tile t+1 into the other buffer; then issue loads for tile t+2
    if (t + 1 < ntiles) {
      #pragma unroll
      for (int i = 0; i < 2; ++i) {
        *(ushort8*)(Ks[1 - cur] + SWZ(srow, scol + i * 8)) = kreg[i];
        *(ushort8*)(Vt[1 - cur] + SWZ(srow, scol + i * 8)) = vreg[i];
      }
      if (t + 2 < ntiles) {
        const int kb2 = (t + 2) * 64;
        #pragma unroll
        for (int i = 0; i < 2; ++i) {
          kreg[i] = *(const ushort8*)(qkv + (size_t)(kb2 + srow) * 3072 + 1024 + hoff +
                                      scol + i * 8);
          vreg[i] = *(const ushort8*)(vT + (size_t)(hoff + srow) * 4096 + kb2 + scol + i * 8);
        }
      }
    }

    // P = exp2(S^T) with causal mask -> wave-private swizzled LDS rows
    const int kb = t * 64;
    strip_exp_store(Ps, s0, kb, qb + wrow, wrow + l16, quad, l16);

    // O^T += V^T P^T ; l += ones^T P^T (row-sum via MFMA)
    __builtin_amdgcn_s_setprio(1);
    #pragma unroll
    for (int ks = 0; ks < 2; ++ks) {
      bf16x8 bp0 = *(const bf16x8*)(Ps + SWZ(wrow + l16, ks * 32 + quad * 8));
      #pragma unroll
      for (int nt = 0; nt < 4; ++nt) {
        bf16x8 av = *(const bf16x8*)(Vt[cur] + SWZ(nt * 16 + l16, ks * 32 + quad * 8));
        o0[nt] = __builtin_amdgcn_mfma_f32_16x16x32_bf16(av, bp0, o0[nt], 0, 0, 0);
      }
      ol0 = __builtin_amdgcn_mfma_f32_16x16x32_bf16(ones, bp0, ol0, 0, 0, 0);
    }
    __builtin_amdgcn_s_setprio(0);
  }

  // l[q=l16] is in every row-slot of ol0; no cross-lane reduce needed.
  const float inv0 = 1.0f / ol0[0];
  // o0[nt][r] = O[q = qb+wrow+l16][d = nt*16+quad*4+r] -> packed stores
  #pragma unroll
  for (int nt = 0; nt < 4; ++nt) {
    ushort4v ov0;
    #pragma unroll
    for (int r = 0; r < 4; ++r) ov0[r] = f2bf(o0[nt][r] * inv0);
    *(ushort4v*)(y + (size_t)(qb + wrow + l16) * 3072 + hoff + nt * 16 + quad * 4) = ov0;
  }
}

extern "C" void kernel_launch(void* const* d_in, const int* in_sizes, int n_in,
                              void* d_out, int out_size, void* d_ws, size_t ws_size,
                              hipStream_t stream) {
  const float* x = (const float*)d_in[0];       // [4096][1024] fp32
  const float* w_qkv = (const float*)d_in[1];   // [1024][3072] fp32
  const float* w_proj = (const float*)d_in[2];  // [1024][1024] fp32
  float* out = (float*)d_out;                   // [4096][1024] fp32

  ushort_t* ws = (ushort_t*)d_ws;
  ushort_t* qkv = ws;                            // [4096][3072]  [0, 24 MiB)
  ushort_t* wqkvT = ws + (size_t)4096 * 3072;    // [3072][1024]  [24, 30 MiB)
  ushort_t* yb = qkv + 2048;                     // strided view into dead V cols (ld 3072)
  ushort_t* wprojT = wqkvT;                      // alias after gemm1
  ushort_t* xb = (ushort_t*)d_out;               // x bf16 in d_out[0,8M)
  ushort_t* vT = (ushort_t*)d_out + (size_t)4096 * 1024;  // [1024][4096] in d_out[8M,16M)

  cvt_f32_bf16<<<4096, 256, 0, stream>>>(x, xb);
  transpose_f32_bf16<<<dim3(96, 32), dim3(32, 8), 0, stream>>>(w_qkv, wqkvT, 1024, 3072);
  gemm_bt_bf16out<<<dim3(24, 32), 256, 0, stream>>>(xb, wqkvT, qkv, vT, 4096, 3072, 1024);
  attn_fwd<<<dim3(16, 64), 256, 0, stream>>>(qkv, vT, yb);
  transpose_f32_bf16<<<dim3(32, 32), dim3(32, 8), 0, stream>>>(w_proj, wprojT, 1024, 1024);
  gemm_bt_f32out<<<dim3(16, 32), 256, 0, stream>>>(yb, wprojT, out, 4096, 1024, 1024, 3072);
}